// Round 6
// baseline (11025.940 us; speedup 1.0000x reference)
//
#include <hip/hip_runtime.h>
#include <hip/hip_bf16.h>
#include <math.h>

typedef __bf16 bf16_t;
typedef __attribute__((ext_vector_type(8))) __bf16 bf16x8;
typedef __attribute__((ext_vector_type(4))) __bf16 bf16x4;
typedef __attribute__((ext_vector_type(4))) float f32x4;

static constexpr int B_ = 16, C_ = 16, T_ = 128, D_ = 256, H_ = 8;
static constexpr int L_ = 12, FF_ = 1024;
static constexpr int NSEQ = C_ * T_ + 1;      // 2049
static constexpr int M_ = B_ * NSEQ;          // 32784
static constexpr int MPAD = 32896;            // row padding for A-buffers
static constexpr float EPS_ = 1e-5f;

__device__ __forceinline__ float wave_sum(float s) {
    #pragma unroll
    for (int o = 1; o < 64; o <<= 1) s += __shfl_xor(s, o);
    return s;
}

// ---------------- weight conversion ----------------
__global__ void conv_qkv(const float* __restrict__ Wq, const float* __restrict__ Wk,
                         const float* __restrict__ Wv, bf16_t* __restrict__ out) {
    size_t i = (size_t)blockIdx.x * 256 + threadIdx.x;
    size_t tot = (size_t)L_ * 768 * 256;
    if (i >= tot) return;
    int k = i & 255;
    int n = (i >> 8) % 768;
    int l = i / (768 * 256);
    const float* src = (n < 256) ? Wq : (n < 512) ? Wk : Wv;
    int nn = n & 255;
    out[i] = (bf16_t)src[((size_t)l * 256 + k) * 256 + nn];
}

__global__ void conv_t(const float* __restrict__ W, bf16_t* __restrict__ out, int R, int Cc) {
    size_t i = (size_t)blockIdx.x * 256 + threadIdx.x;
    size_t tot = (size_t)L_ * R * Cc;
    if (i >= tot) return;
    int r = i % R;
    int c = (i / R) % Cc;
    int l = i / ((size_t)R * Cc);
    out[i] = (bf16_t)W[((size_t)l * R + r) * Cc + c];
}

// ---------------- embedding ----------------
__global__ void embed_kernel(const int* __restrict__ x, const float* __restrict__ emb,
                             const float* __restrict__ ch, const float* __restrict__ cls,
                             float* __restrict__ h) {
    int wave = threadIdx.x >> 6, lane = threadIdx.x & 63;
    int row = blockIdx.x * 4 + wave;
    int d0 = lane * 4;
    float4 o;
    int b = row / NSEQ, n = row % NSEQ;
    if (n == 0) {
        o = *(const float4*)(cls + d0);
    } else {
        int idx = n - 1;
        int c = idx / T_, t = idx % T_;
        int tok = x[(b * C_ + c) * T_ + t];
        float4 ev = *(const float4*)(emb + (size_t)tok * 256 + d0);
        float4 cv = *(const float4*)(ch + c * 256 + d0);
        const float kdiv = -0.03597789207803197f;   // -ln(10000)/256
        float f0 = __expf(d0 * kdiv);
        float f2 = __expf((d0 + 2) * kdiv);
        float a0 = t * f0, a2 = t * f2;
        o.x = ev.x + cv.x + sinf(a0);
        o.y = ev.y + cv.y + cosf(a0);
        o.z = ev.z + cv.z + sinf(a2);
        o.w = ev.w + cv.w + cosf(a2);
    }
    *(float4*)(h + (size_t)row * 256 + d0) = o;
}

// ---------------- layer norm -> bf16 ----------------
__global__ void ln_kernel(const float* __restrict__ h, const float* __restrict__ g,
                          const float* __restrict__ bb, bf16_t* __restrict__ out) {
    int wave = threadIdx.x >> 6, lane = threadIdx.x & 63;
    int row = blockIdx.x * 4 + wave;
    const float* xp = h + (size_t)row * 256;
    int d0 = lane * 4;
    float4 v = *(const float4*)(xp + d0);
    float s = wave_sum(v.x + v.y + v.z + v.w);
    float mean = s * (1.f / 256.f);
    float4 d;
    d.x = v.x - mean; d.y = v.y - mean; d.z = v.z - mean; d.w = v.w - mean;
    float q = wave_sum(d.x * d.x + d.y * d.y + d.z * d.z + d.w * d.w);
    float rs = rsqrtf(q * (1.f / 256.f) + EPS_);
    float4 gv = *(const float4*)(g + d0);
    float4 bv = *(const float4*)(bb + d0);
    bf16x4 o4;
    o4[0] = (bf16_t)(d.x * rs * gv.x + bv.x);
    o4[1] = (bf16_t)(d.y * rs * gv.y + bv.y);
    o4[2] = (bf16_t)(d.z * rs * gv.z + bv.z);
    o4[3] = (bf16_t)(d.w * rs * gv.w + bv.w);
    *(bf16x4*)(out + (size_t)row * 256 + d0) = o4;
}

// ============================================================================
// Barrier-free, LDS-free weight-stream GEMM (named regs, no spillable arrays).
// A [MPAD][K] bf16 row-major, Bt [N][K] bf16 (weights, L2-hot).
// Block = 8 waves (512 thr); wave w owns 64 rows x 16 cols:
//   rows r0..r0+63 (r0 = by*64), col = bx*128 + w*16 + (lane&15).
// Per 32-k chunk: 1 B-frag + 4 A-frags loaded global->reg, 4 MFMAs.
// Grid (N/128, 513), m204 bijective XCD swizzle: each XCD owns a
// contiguous row strip -> A-window L2-resident, fetched ~once.
//  EPI 0: Cb = bf16(acc)   EPI 1: Cf += acc + bias   EPI 2: Cb = bf16(gelu(acc+bias))
// ============================================================================
template <int EPI, int KC>   // K = KC*32
__launch_bounds__(512, 4)
__global__ void gemm_ws(const bf16_t* __restrict__ A, const bf16_t* __restrict__ Bt,
                        float* __restrict__ Cf, bf16_t* __restrict__ Cb,
                        const float* __restrict__ bias, int N) {
    constexpr int K = KC * 32;
    int gx = gridDim.x;
    int nwg = gx * gridDim.y;
    int lin = blockIdx.y * gx + blockIdx.x;
    int qq = nwg >> 3, rr = nwg & 7;
    int xcd = lin & 7, idx = lin >> 3;
    int wg = (xcd < rr ? xcd * (qq + 1) : rr * (qq + 1) + (xcd - rr) * qq) + idx;
    int bx = wg % gx, by = wg / gx;

    int lane = threadIdx.x & 63, wave = threadIdx.x >> 6;
    int r0 = by * 64;
    int col = bx * 128 + wave * 16 + (lane & 15);
    int kofs = (lane >> 4) * 8;
    const bf16_t* Bp = Bt + (size_t)col * K + kofs;
    const bf16_t* Ap = A + (size_t)(r0 + (lane & 15)) * K + kofs;

    f32x4 acc0 = {}, acc1 = {}, acc2 = {}, acc3 = {};
    #pragma unroll
    for (int kc = 0; kc < KC; ++kc) {
        int kb = kc * 32;
        bf16x8 bfv = *(const bf16x8*)(Bp + kb);
        bf16x8 a0 = *(const bf16x8*)(Ap + kb);
        bf16x8 a1 = *(const bf16x8*)(Ap + kb + (size_t)16 * K);
        bf16x8 a2 = *(const bf16x8*)(Ap + kb + (size_t)32 * K);
        bf16x8 a3 = *(const bf16x8*)(Ap + kb + (size_t)48 * K);
        acc0 = __builtin_amdgcn_mfma_f32_16x16x32_bf16(a0, bfv, acc0, 0, 0, 0);
        acc1 = __builtin_amdgcn_mfma_f32_16x16x32_bf16(a1, bfv, acc1, 0, 0, 0);
        acc2 = __builtin_amdgcn_mfma_f32_16x16x32_bf16(a2, bfv, acc2, 0, 0, 0);
        acc3 = __builtin_amdgcn_mfma_f32_16x16x32_bf16(a3, bfv, acc3, 0, 0, 0);
    }

    float bv = (EPI != 0) ? bias[col] : 0.f;
    int rq = (lane >> 4) << 2;
#define WS_EPILOG(ACC, MF)                                                     \
    {                                                                          \
        _Pragma("unroll")                                                      \
        for (int i = 0; i < 4; ++i) {                                          \
            int r = r0 + (MF) * 16 + rq + i;                                   \
            if (r < M_) {                                                      \
                float v = ACC[i] + bv;                                         \
                if (EPI == 0) {                                                \
                    Cb[(size_t)r * N + col] = (bf16_t)v;                       \
                } else if (EPI == 1) {                                         \
                    Cf[(size_t)r * N + col] += v;                              \
                } else {                                                       \
                    float gl = 0.5f * v * (1.f + erff(v * 0.70710678118654752f)); \
                    Cb[(size_t)r * N + col] = (bf16_t)gl;                      \
                }                                                              \
            }                                                                  \
        }                                                                      \
    }
    WS_EPILOG(acc0, 0)
    WS_EPILOG(acc1, 1)
    WS_EPILOG(acc2, 2)
    WS_EPILOG(acc3, 3)
#undef WS_EPILOG
}

// ---------------- k column max (over n) ----------------
__global__ void kmax_kernel(const bf16_t* __restrict__ qkv, float* __restrict__ colmax) {
    int bh = blockIdx.x;                 // b*8+h
    int b = bh >> 3, hh = bh & 7;
    int c = threadIdx.x & 31, stripe = threadIdx.x >> 5;
    const bf16_t* base = qkv + (size_t)b * NSEQ * 768 + 256 + hh * 32;
    float m = -1e30f;
    for (int n = stripe; n < NSEQ; n += 8)
        m = fmaxf(m, (float)base[(size_t)n * 768 + c]);
    __shared__ float red[8][32];
    red[stripe][c] = m;
    __syncthreads();
    if (threadIdx.x < 32) {
        float mm = red[0][c];
        #pragma unroll
        for (int s2 = 1; s2 < 8; ++s2) mm = fmaxf(mm, red[s2][c]);
        colmax[bh * 32 + c] = mm;
    }
}

// ---------------- ctx partial: sum_n exp(k-max)*v ; colsum ----------------
__global__ void ctx_kernel(const bf16_t* __restrict__ qkv, const float* __restrict__ colmax,
                           float* __restrict__ ctx_part, float* __restrict__ colsum_part) {
    int blk = blockIdx.x;                // bh*8 + s
    int bh = blk >> 3, s = blk & 7;
    int b = bh >> 3, hh = bh & 7;
    int n0 = s * 257, n1 = min(n0 + 257, NSEQ);
    int d = threadIdx.x & 31, eg = threadIdx.x >> 5;
    float maxd = colmax[bh * 32 + d];
    float acc[4] = {0.f, 0.f, 0.f, 0.f};
    float ksum = 0.f;
    __shared__ float ks[64][32];
    __shared__ float vs[64][32];
    const bf16_t* kbase = qkv + (size_t)b * NSEQ * 768 + 256 + hh * 32;
    const bf16_t* vbase = kbase + 256;
    int lr = threadIdx.x >> 2, lc = (threadIdx.x & 3) * 8;
    for (int c0 = n0; c0 < n1; c0 += 64) {
        int rows = min(64, n1 - c0);
        if (lr < rows) {
            bf16x8 kv8 = *(const bf16x8*)(kbase + (size_t)(c0 + lr) * 768 + lc);
            bf16x8 vv8 = *(const bf16x8*)(vbase + (size_t)(c0 + lr) * 768 + lc);
            #pragma unroll
            for (int j = 0; j < 8; ++j) {
                ks[lr][lc + j] = (float)kv8[j];
                vs[lr][lc + j] = (float)vv8[j];
            }
        }
        __syncthreads();
        for (int r = 0; r < rows; ++r) {
            float ek = __expf(ks[r][d] - maxd);
            if (eg == 0) ksum += ek;
            const float* vr = &vs[r][eg * 4];
            acc[0] += ek * vr[0]; acc[1] += ek * vr[1];
            acc[2] += ek * vr[2]; acc[3] += ek * vr[3];
        }
        __syncthreads();
    }
    float* cp = ctx_part + ((size_t)blk * 32 + d) * 32 + eg * 4;
    cp[0] = acc[0]; cp[1] = acc[1]; cp[2] = acc[2]; cp[3] = acc[3];
    if (eg == 0) colsum_part[blk * 32 + d] = ksum;
}

// ---------------- o = softmax(q)*scale @ ctx  -> bf16 [M][256] ----------------
__global__ void o_kernel(const bf16_t* __restrict__ qkv, const float* __restrict__ ctx_part,
                         const float* __restrict__ colsum_part, bf16_t* __restrict__ o) {
    int bh = blockIdx.x, b = bh >> 3, hh = bh & 7;
    int chunk = blockIdx.y;
    __shared__ float ctx[1024];
    __shared__ float csum[32];
    int t = threadIdx.x;
    if (t < 32) {
        float s = 0.f;
        #pragma unroll
        for (int ss = 0; ss < 8; ++ss) s += colsum_part[(bh * 8 + ss) * 32 + t];
        csum[t] = s;
    }
    __syncthreads();
    for (int i = t; i < 1024; i += 256) {
        float s = 0.f;
        #pragma unroll
        for (int ss = 0; ss < 8; ++ss) s += ctx_part[(size_t)(bh * 8 + ss) * 1024 + i];
        ctx[i] = s / csum[i >> 5];
    }
    __syncthreads();
    int e = t & 31, grp = t >> 5;
    int n0 = chunk * 228, n1 = min(n0 + 228, NSEQ);
    for (int n = n0 + grp; n < n1; n += 8) {
        const bf16_t* q = qkv + (size_t)(b * NSEQ + n) * 768 + hh * 32;
        float qv = (float)q[e];
        float mx = qv;
        #pragma unroll
        for (int o2 = 16; o2 > 0; o2 >>= 1) mx = fmaxf(mx, __shfl_xor(mx, o2, 32));
        float ev = __expf(qv - mx);
        float sm = ev;
        #pragma unroll
        for (int o2 = 16; o2 > 0; o2 >>= 1) sm += __shfl_xor(sm, o2, 32);
        float p = ev * 0.17677669529663689f / sm;   // dh^-0.5 / sum
        float s = 0.f;
        #pragma unroll
        for (int dd = 0; dd < 32; ++dd) s += __shfl(p, dd, 32) * ctx[dd * 32 + e];
        o[(size_t)(b * NSEQ + n) * 256 + hh * 32 + e] = (bf16_t)s;
    }
}

// ---------------- classifier head: one wave per (b, cls) ----------------
__global__ void head_kernel(const float* __restrict__ h, const float* __restrict__ Wh,
                            const float* __restrict__ bh, float* __restrict__ out) {
    int idx = blockIdx.x;                 // 0..79 = b*5 + c
    int b = idx / 5, c = idx % 5;
    int lane = threadIdx.x;
    const float* xp = h + (size_t)b * NSEQ * 256;
    float s = 0.f;
    #pragma unroll
    for (int d0 = 0; d0 < 256; d0 += 64) s += xp[d0 + lane] * Wh[(d0 + lane) * 5 + c];
    s = wave_sum(s);
    if (lane == 0) out[idx] = s + bh[c];
}

extern "C" void kernel_launch(void* const* d_in, const int* in_sizes, int n_in,
                              void* d_out, int out_size, void* d_ws, size_t ws_size,
                              hipStream_t stream) {
    const int*   x    = (const int*)d_in[0];
    const float* emb  = (const float*)d_in[1];
    const float* ch   = (const float*)d_in[2];
    const float* cls  = (const float*)d_in[3];
    const float* Wq   = (const float*)d_in[4];
    const float* Wk   = (const float*)d_in[5];
    const float* Wv   = (const float*)d_in[6];
    const float* Wo   = (const float*)d_in[7];
    const float* bo   = (const float*)d_in[8];
    const float* g1   = (const float*)d_in[9];
    const float* b1   = (const float*)d_in[10];
    const float* W1   = (const float*)d_in[11];
    const float* bf1  = (const float*)d_in[12];
    const float* W2   = (const float*)d_in[13];
    const float* bf2  = (const float*)d_in[14];
    const float* g2   = (const float*)d_in[15];
    const float* b2   = (const float*)d_in[16];
    const float* Wh   = (const float*)d_in[17];
    const float* bh   = (const float*)d_in[18];

    char* ws = (char*)d_ws;
    size_t off = 0;
    float*  h      = (float*)(ws + off);  off += (size_t)M_ * 256 * 4;            // 33,570,816
    bf16_t* yn     = (bf16_t*)(ws + off); off += (size_t)MPAD * 256 * 2;          // 16,842,752
    bf16_t* qkv    = (bf16_t*)(ws + off);
    bf16_t* f1     = (bf16_t*)(ws + off); off += (size_t)MPAD * 1024 * 2;         // 67,371,008 (f1 aliases qkv)
    float*  ctxp   = (float*)(ws + off);  off += (size_t)16 * 8 * 8 * 1024 * 4;   // 4,194,304
    float*  csump  = (float*)(ws + off);  off += (size_t)16 * 8 * 8 * 32 * 4;     // 131,072
    float*  cmax   = (float*)(ws + off);  off += (size_t)16 * 8 * 32 * 4;         // 16,384
    bf16_t* wqkv_t = (bf16_t*)(ws + off); off += (size_t)L_ * 768 * 256 * 2;      // 4,718,592
    bf16_t* wo_t   = (bf16_t*)(ws + off); off += (size_t)L_ * 256 * 256 * 2;      // 1,572,864
    bf16_t* w1_t   = (bf16_t*)(ws + off); off += (size_t)L_ * 1024 * 256 * 2;     // 6,291,456
    bf16_t* w2_t   = (bf16_t*)(ws + off); off += (size_t)L_ * 256 * 1024 * 2;     // 6,291,456
    (void)ws_size; (void)in_sizes; (void)n_in; (void)out_size;

    conv_qkv<<<9216, 256, 0, stream>>>(Wq, Wk, Wv, wqkv_t);
    conv_t<<<3072, 256, 0, stream>>>(Wo, wo_t, 256, 256);
    conv_t<<<12288, 256, 0, stream>>>(W1, w1_t, 256, 1024);
    conv_t<<<12288, 256, 0, stream>>>(W2, w2_t, 1024, 256);

    embed_kernel<<<M_ / 4, 256, 0, stream>>>(x, emb, ch, cls, h);

    constexpr int RB = 513;   // 64-row strips
    for (int l = 0; l < L_; ++l) {
        // LN1 -> yn bf16
        ln_kernel<<<M_ / 4, 256, 0, stream>>>(h, g1 + l * 256, b1 + l * 256, yn);
        // QKV: yn @ wqkv^T -> qkv bf16 [M][768]
        gemm_ws<0, 8><<<dim3(6, RB), 512, 0, stream>>>(yn, wqkv_t + (size_t)l * 768 * 256,
                                                       nullptr, qkv, nullptr, 768);
        kmax_kernel<<<128, 256, 0, stream>>>(qkv, cmax);
        ctx_kernel<<<1024, 256, 0, stream>>>(qkv, cmax, ctxp, csump);
        o_kernel<<<dim3(128, 9), 256, 0, stream>>>(qkv, ctxp, csump, yn);
        // Wo: yn(attn out) @ wo^T + bo, residual += into h
        gemm_ws<1, 8><<<dim3(2, RB), 512, 0, stream>>>(yn, wo_t + (size_t)l * 256 * 256,
                                                       h, nullptr, bo + l * 256, 256);
        // LN2 -> yn bf16
        ln_kernel<<<M_ / 4, 256, 0, stream>>>(h, g2 + l * 256, b2 + l * 256, yn);
        // FF1: yn @ w1^T + bf1, gelu -> f1 bf16 [M][1024]
        gemm_ws<2, 8><<<dim3(8, RB), 512, 0, stream>>>(yn, w1_t + (size_t)l * 1024 * 256,
                                                       nullptr, f1, bf1 + l * 1024, 1024);
        // FF2: f1 @ w2^T + bf2, residual += into h
        gemm_ws<1, 32><<<dim3(2, RB), 512, 0, stream>>>(f1, w2_t + (size_t)l * 256 * 1024,
                                                        h, nullptr, bf2 + l * 256, 256);
    }

    head_kernel<<<80, 64, 0, stream>>>(h, Wh, bh, (float*)d_out);
}

// Round 7
// 4548.321 us; speedup vs baseline: 2.4242x; 2.4242x over previous
//
#include <hip/hip_runtime.h>
#include <hip/hip_bf16.h>
#include <math.h>

typedef __bf16 bf16_t;
typedef __attribute__((ext_vector_type(8))) __bf16 bf16x8;
typedef __attribute__((ext_vector_type(4))) __bf16 bf16x4;
typedef __attribute__((ext_vector_type(4))) float f32x4;

static constexpr int B_ = 16, C_ = 16, T_ = 128, D_ = 256, H_ = 8;
static constexpr int L_ = 12, FF_ = 1024;
static constexpr int NSEQ = C_ * T_ + 1;      // 2049
static constexpr int M_ = B_ * NSEQ;          // 32784
static constexpr int MPAD = 32896;            // 257*128
static constexpr float EPS_ = 1e-5f;

__device__ __forceinline__ float wave_sum(float s) {
    #pragma unroll
    for (int o = 1; o < 64; o <<= 1) s += __shfl_xor(s, o);
    return s;
}

// ---------------- weight conversion ----------------
__global__ void conv_qkv(const float* __restrict__ Wq, const float* __restrict__ Wk,
                         const float* __restrict__ Wv, bf16_t* __restrict__ out) {
    size_t i = (size_t)blockIdx.x * 256 + threadIdx.x;
    size_t tot = (size_t)L_ * 768 * 256;
    if (i >= tot) return;
    int k = i & 255;
    int n = (i >> 8) % 768;
    int l = i / (768 * 256);
    const float* src = (n < 256) ? Wq : (n < 512) ? Wk : Wv;
    int nn = n & 255;
    out[i] = (bf16_t)src[((size_t)l * 256 + k) * 256 + nn];
}

__global__ void conv_t(const float* __restrict__ W, bf16_t* __restrict__ out, int R, int Cc) {
    size_t i = (size_t)blockIdx.x * 256 + threadIdx.x;
    size_t tot = (size_t)L_ * R * Cc;
    if (i >= tot) return;
    int r = i % R;
    int c = (i / R) % Cc;
    int l = i / ((size_t)R * Cc);
    out[i] = (bf16_t)W[((size_t)l * R + r) * Cc + c];
}

// ---------------- embedding ----------------
__global__ void embed_kernel(const int* __restrict__ x, const float* __restrict__ emb,
                             const float* __restrict__ ch, const float* __restrict__ cls,
                             float* __restrict__ h) {
    int wave = threadIdx.x >> 6, lane = threadIdx.x & 63;
    int row = blockIdx.x * 4 + wave;
    int d0 = lane * 4;
    float4 o;
    int b = row / NSEQ, n = row % NSEQ;
    if (n == 0) {
        o = *(const float4*)(cls + d0);
    } else {
        int idx = n - 1;
        int c = idx / T_, t = idx % T_;
        int tok = x[(b * C_ + c) * T_ + t];
        float4 ev = *(const float4*)(emb + (size_t)tok * 256 + d0);
        float4 cv = *(const float4*)(ch + c * 256 + d0);
        const float kdiv = -0.03597789207803197f;   // -ln(10000)/256
        float f0 = __expf(d0 * kdiv);
        float f2 = __expf((d0 + 2) * kdiv);
        float a0 = t * f0, a2 = t * f2;
        o.x = ev.x + cv.x + sinf(a0);
        o.y = ev.y + cv.y + cosf(a0);
        o.z = ev.z + cv.z + sinf(a2);
        o.w = ev.w + cv.w + cosf(a2);
    }
    *(float4*)(h + (size_t)row * 256 + d0) = o;
}

// ---------------- layer norm -> bf16 ----------------
__global__ void ln_kernel(const float* __restrict__ h, const float* __restrict__ g,
                          const float* __restrict__ bb, bf16_t* __restrict__ out) {
    int wave = threadIdx.x >> 6, lane = threadIdx.x & 63;
    int row = blockIdx.x * 4 + wave;
    const float* xp = h + (size_t)row * 256;
    int d0 = lane * 4;
    float4 v = *(const float4*)(xp + d0);
    float s = wave_sum(v.x + v.y + v.z + v.w);
    float mean = s * (1.f / 256.f);
    float4 d;
    d.x = v.x - mean; d.y = v.y - mean; d.z = v.z - mean; d.w = v.w - mean;
    float q = wave_sum(d.x * d.x + d.y * d.y + d.z * d.z + d.w * d.w);
    float rs = rsqrtf(q * (1.f / 256.f) + EPS_);
    float4 gv = *(const float4*)(g + d0);
    float4 bv = *(const float4*)(bb + d0);
    bf16x4 o4;
    o4[0] = (bf16_t)(d.x * rs * gv.x + bv.x);
    o4[1] = (bf16_t)(d.y * rs * gv.y + bv.y);
    o4[2] = (bf16_t)(d.z * rs * gv.z + bv.z);
    o4[3] = (bf16_t)(d.w * rs * gv.w + bv.w);
    *(bf16x4*)(out + (size_t)row * 256 + d0) = o4;
}

// ============================================================================
// Register-staged LDS GEMM (T14 structure).
// A [MPAD][K] bf16, Bt [N][K] bf16.  128x128 tile, BK=64, 256 threads.
// Per K-step: each thread global-loads its 64B share of next A/B tile
// (4+4 coalesced dwordx4 -> 8KB/wave in flight), MFMAs on current LDS buffer,
// then vmcnt-waited ds_write of the prefetch; ONE barrier per K-step.
// LDS XOR-swizzle (chunk ^= row&7) on both write and read -> <=2-way conflicts.
// XCD chunk swizzle (m204): each XCD owns contiguous row-stripes.
//  EPI 0: Cb = bf16(acc)   EPI 1: Cf += acc + bias   EPI 2: Cb = bf16(gelu(acc+bias))
// ============================================================================
template <int EPI, int NK>   // K = NK*64
__launch_bounds__(256, 2)
__global__ void gemm_rs(const bf16_t* __restrict__ A, const bf16_t* __restrict__ Bt,
                        float* __restrict__ Cf, bf16_t* __restrict__ Cb,
                        const float* __restrict__ bias, int N) {
    constexpr int K = NK * 64;
    __shared__ bf16_t As[2][128 * 64];
    __shared__ bf16_t Bs[2][128 * 64];

    int NC = gridDim.x;
    int nwg = NC * gridDim.y;
    int lin = blockIdx.y * NC + blockIdx.x;
    int q = nwg >> 3, rr = nwg & 7;
    int xcd = lin & 7, sidx = lin >> 3;
    int wg = (xcd < rr ? xcd * (q + 1) : rr * (q + 1) + (xcd - rr) * q) + sidx;
    int col0 = (wg % NC) * 128;
    int row0 = (wg / NC) * 128;

    int tid = threadIdx.x;
    int lane = tid & 63, wave = tid >> 6;
    int wr = wave >> 1, wc = wave & 1;

    // staging mapping: thread covers 64B of one row (2 threads/row)
    int srow = tid >> 1, half = tid & 1;
    const bf16_t* Aq = A + (size_t)(row0 + srow) * K + half * 32;
    const bf16_t* Bq = Bt + (size_t)(col0 + srow) * K + half * 32;
    int sx = srow & 7;
    int sw0 = (((half * 4 + 0) ^ sx) << 3);
    int sw1 = (((half * 4 + 1) ^ sx) << 3);
    int sw2 = (((half * 4 + 2) ^ sx) << 3);
    int sw3 = (((half * 4 + 3) ^ sx) << 3);
    int sbase = srow * 64;

    // fragment read bases
    int l15 = lane & 15, ksel = lane >> 4;
    int ar0 = wr * 64 + l15,      ao0 = ar0 * 64, ax0 = ar0 & 7;
    int ar1 = wr * 64 + 16 + l15, ao1 = ar1 * 64, ax1 = ar1 & 7;
    int ar2 = wr * 64 + 32 + l15, ao2 = ar2 * 64, ax2 = ar2 & 7;
    int ar3 = wr * 64 + 48 + l15, ao3 = ar3 * 64, ax3 = ar3 & 7;
    int br0 = wc * 64 + l15,      bo0 = br0 * 64, bx0 = br0 & 7;
    int br1 = wc * 64 + 16 + l15, bo1 = br1 * 64, bx1 = br1 & 7;
    int br2 = wc * 64 + 32 + l15, bo2 = br2 * 64, bx2 = br2 & 7;
    int br3 = wc * 64 + 48 + l15, bo3 = br3 * 64, bx3 = br3 & 7;

    bf16x8 sa0, sa1, sa2, sa3, sb0, sb1, sb2, sb3;
    f32x4 acc[4][4] = {};

#define GLD(t) do {                                                            \
        const bf16_t* ap_ = Aq + (t) * 64;                                     \
        const bf16_t* bp_ = Bq + (t) * 64;                                     \
        sa0 = *(const bf16x8*)(ap_ + 0);  sa1 = *(const bf16x8*)(ap_ + 8);     \
        sa2 = *(const bf16x8*)(ap_ + 16); sa3 = *(const bf16x8*)(ap_ + 24);    \
        sb0 = *(const bf16x8*)(bp_ + 0);  sb1 = *(const bf16x8*)(bp_ + 8);     \
        sb2 = *(const bf16x8*)(bp_ + 16); sb3 = *(const bf16x8*)(bp_ + 24);    \
    } while (0)

#define LWRITE(bi) do {                                                        \
        bf16_t* as_ = As[bi]; bf16_t* bs_ = Bs[bi];                            \
        *(bf16x8*)(as_ + sbase + sw0) = sa0; *(bf16x8*)(as_ + sbase + sw1) = sa1; \
        *(bf16x8*)(as_ + sbase + sw2) = sa2; *(bf16x8*)(as_ + sbase + sw3) = sa3; \
        *(bf16x8*)(bs_ + sbase + sw0) = sb0; *(bf16x8*)(bs_ + sbase + sw1) = sb1; \
        *(bf16x8*)(bs_ + sbase + sw2) = sb2; *(bf16x8*)(bs_ + sbase + sw3) = sb3; \
    } while (0)

#define CMP(bi) do {                                                           \
        const bf16_t* as_ = As[bi]; const bf16_t* bs_ = Bs[bi];                \
        _Pragma("unroll")                                                      \
        for (int kk = 0; kk < 2; ++kk) {                                       \
            int c_ = kk * 4 + ksel;                                            \
            bf16x8 af0 = *(const bf16x8*)(as_ + ao0 + ((c_ ^ ax0) << 3));      \
            bf16x8 af1 = *(const bf16x8*)(as_ + ao1 + ((c_ ^ ax1) << 3));      \
            bf16x8 af2 = *(const bf16x8*)(as_ + ao2 + ((c_ ^ ax2) << 3));      \
            bf16x8 af3 = *(const bf16x8*)(as_ + ao3 + ((c_ ^ ax3) << 3));      \
            bf16x8 bf0 = *(const bf16x8*)(bs_ + bo0 + ((c_ ^ bx0) << 3));      \
            bf16x8 bf1 = *(const bf16x8*)(bs_ + bo1 + ((c_ ^ bx1) << 3));      \
            bf16x8 bf2 = *(const bf16x8*)(bs_ + bo2 + ((c_ ^ bx2) << 3));      \
            bf16x8 bf3 = *(const bf16x8*)(bs_ + bo3 + ((c_ ^ bx3) << 3));      \
            acc[0][0] = __builtin_amdgcn_mfma_f32_16x16x32_bf16(af0, bf0, acc[0][0], 0, 0, 0); \
            acc[0][1] = __builtin_amdgcn_mfma_f32_16x16x32_bf16(af0, bf1, acc[0][1], 0, 0, 0); \
            acc[0][2] = __builtin_amdgcn_mfma_f32_16x16x32_bf16(af0, bf2, acc[0][2], 0, 0, 0); \
            acc[0][3] = __builtin_amdgcn_mfma_f32_16x16x32_bf16(af0, bf3, acc[0][3], 0, 0, 0); \
            acc[1][0] = __builtin_amdgcn_mfma_f32_16x16x32_bf16(af1, bf0, acc[1][0], 0, 0, 0); \
            acc[1][1] = __builtin_amdgcn_mfma_f32_16x16x32_bf16(af1, bf1, acc[1][1], 0, 0, 0); \
            acc[1][2] = __builtin_amdgcn_mfma_f32_16x16x32_bf16(af1, bf2, acc[1][2], 0, 0, 0); \
            acc[1][3] = __builtin_amdgcn_mfma_f32_16x16x32_bf16(af1, bf3, acc[1][3], 0, 0, 0); \
            acc[2][0] = __builtin_amdgcn_mfma_f32_16x16x32_bf16(af2, bf0, acc[2][0], 0, 0, 0); \
            acc[2][1] = __builtin_amdgcn_mfma_f32_16x16x32_bf16(af2, bf1, acc[2][1], 0, 0, 0); \
            acc[2][2] = __builtin_amdgcn_mfma_f32_16x16x32_bf16(af2, bf2, acc[2][2], 0, 0, 0); \
            acc[2][3] = __builtin_amdgcn_mfma_f32_16x16x32_bf16(af2, bf3, acc[2][3], 0, 0, 0); \
            acc[3][0] = __builtin_amdgcn_mfma_f32_16x16x32_bf16(af3, bf0, acc[3][0], 0, 0, 0); \
            acc[3][1] = __builtin_amdgcn_mfma_f32_16x16x32_bf16(af3, bf1, acc[3][1], 0, 0, 0); \
            acc[3][2] = __builtin_amdgcn_mfma_f32_16x16x32_bf16(af3, bf2, acc[3][2], 0, 0, 0); \
            acc[3][3] = __builtin_amdgcn_mfma_f32_16x16x32_bf16(af3, bf3, acc[3][3], 0, 0, 0); \
        }                                                                      \
    } while (0)

    GLD(0);
    LWRITE(0);
    __syncthreads();
    int cur = 0;
    #pragma unroll
    for (int t = 0; t < NK; ++t) {
        if (t + 1 < NK) GLD(t + 1);
        CMP(cur);
        if (t + 1 < NK) LWRITE(cur ^ 1);
        __syncthreads();
        cur ^= 1;
    }
#undef GLD
#undef LWRITE
#undef CMP

    #pragma unroll
    for (int m = 0; m < 4; ++m) {
        int rbase = row0 + wr * 64 + m * 16 + (ksel << 2);
        #pragma unroll
        for (int n = 0; n < 4; ++n) {
            int c = col0 + wc * 64 + n * 16 + l15;
            float bv = (EPI != 0) ? bias[c] : 0.f;
            #pragma unroll
            for (int i = 0; i < 4; ++i) {
                int r = rbase + i;
                if (r < M_) {
                    float v = acc[m][n][i] + bv;
                    if (EPI == 0) {
                        Cb[(size_t)r * N + c] = (bf16_t)v;
                    } else if (EPI == 1) {
                        Cf[(size_t)r * N + c] += v;
                    } else {
                        float gl = 0.5f * v * (1.f + erff(v * 0.70710678118654752f));
                        Cb[(size_t)r * N + c] = (bf16_t)gl;
                    }
                }
            }
        }
    }
}

// ---------------- k column max (over n) ----------------
__global__ void kmax_kernel(const bf16_t* __restrict__ qkv, float* __restrict__ colmax) {
    int bh = blockIdx.x;                 // b*8+h
    int b = bh >> 3, hh = bh & 7;
    int c = threadIdx.x & 31, stripe = threadIdx.x >> 5;
    const bf16_t* base = qkv + (size_t)b * NSEQ * 768 + 256 + hh * 32;
    float m = -1e30f;
    for (int n = stripe; n < NSEQ; n += 8)
        m = fmaxf(m, (float)base[(size_t)n * 768 + c]);
    __shared__ float red[8][32];
    red[stripe][c] = m;
    __syncthreads();
    if (threadIdx.x < 32) {
        float mm = red[0][c];
        #pragma unroll
        for (int s2 = 1; s2 < 8; ++s2) mm = fmaxf(mm, red[s2][c]);
        colmax[bh * 32 + c] = mm;
    }
}

// ---------------- ctx partial: sum_n exp(k-max)*v ; colsum ----------------
__global__ void ctx_kernel(const bf16_t* __restrict__ qkv, const float* __restrict__ colmax,
                           float* __restrict__ ctx_part, float* __restrict__ colsum_part) {
    int blk = blockIdx.x;                // bh*8 + s
    int bh = blk >> 3, s = blk & 7;
    int b = bh >> 3, hh = bh & 7;
    int n0 = s * 257, n1 = min(n0 + 257, NSEQ);
    int d = threadIdx.x & 31, eg = threadIdx.x >> 5;
    float maxd = colmax[bh * 32 + d];
    float acc[4] = {0.f, 0.f, 0.f, 0.f};
    float ksum = 0.f;
    __shared__ float ks[64][32];
    __shared__ float vs[64][32];
    const bf16_t* kbase = qkv + (size_t)b * NSEQ * 768 + 256 + hh * 32;
    const bf16_t* vbase = kbase + 256;
    int lr = threadIdx.x >> 2, lc = (threadIdx.x & 3) * 8;
    for (int c0 = n0; c0 < n1; c0 += 64) {
        int rows = min(64, n1 - c0);
        if (lr < rows) {
            bf16x8 kv8 = *(const bf16x8*)(kbase + (size_t)(c0 + lr) * 768 + lc);
            bf16x8 vv8 = *(const bf16x8*)(vbase + (size_t)(c0 + lr) * 768 + lc);
            #pragma unroll
            for (int j = 0; j < 8; ++j) {
                ks[lr][lc + j] = (float)kv8[j];
                vs[lr][lc + j] = (float)vv8[j];
            }
        }
        __syncthreads();
        for (int r = 0; r < rows; ++r) {
            float ek = __expf(ks[r][d] - maxd);
            if (eg == 0) ksum += ek;
            const float* vr = &vs[r][eg * 4];
            acc[0] += ek * vr[0]; acc[1] += ek * vr[1];
            acc[2] += ek * vr[2]; acc[3] += ek * vr[3];
        }
        __syncthreads();
    }
    float* cp = ctx_part + ((size_t)blk * 32 + d) * 32 + eg * 4;
    cp[0] = acc[0]; cp[1] = acc[1]; cp[2] = acc[2]; cp[3] = acc[3];
    if (eg == 0) colsum_part[blk * 32 + d] = ksum;
}

// ---------------- o = softmax(q)*scale @ ctx  -> bf16 [M][256] ----------------
__global__ void o_kernel(const bf16_t* __restrict__ qkv, const float* __restrict__ ctx_part,
                         const float* __restrict__ colsum_part, bf16_t* __restrict__ o) {
    int bh = blockIdx.x, b = bh >> 3, hh = bh & 7;
    int chunk = blockIdx.y;
    __shared__ float ctx[1024];
    __shared__ float csum[32];
    int t = threadIdx.x;
    if (t < 32) {
        float s = 0.f;
        #pragma unroll
        for (int ss = 0; ss < 8; ++ss) s += colsum_part[(bh * 8 + ss) * 32 + t];
        csum[t] = s;
    }
    __syncthreads();
    for (int i = t; i < 1024; i += 256) {
        float s = 0.f;
        #pragma unroll
        for (int ss = 0; ss < 8; ++ss) s += ctx_part[(size_t)(bh * 8 + ss) * 1024 + i];
        ctx[i] = s / csum[i >> 5];
    }
    __syncthreads();
    int e = t & 31, grp = t >> 5;
    int n0 = chunk * 228, n1 = min(n0 + 228, NSEQ);
    for (int n = n0 + grp; n < n1; n += 8) {
        const bf16_t* q = qkv + (size_t)(b * NSEQ + n) * 768 + hh * 32;
        float qv = (float)q[e];
        float mx = qv;
        #pragma unroll
        for (int o2 = 16; o2 > 0; o2 >>= 1) mx = fmaxf(mx, __shfl_xor(mx, o2, 32));
        float ev = __expf(qv - mx);
        float sm = ev;
        #pragma unroll
        for (int o2 = 16; o2 > 0; o2 >>= 1) sm += __shfl_xor(sm, o2, 32);
        float p = ev * 0.17677669529663689f / sm;   // dh^-0.5 / sum
        float s = 0.f;
        #pragma unroll
        for (int dd = 0; dd < 32; ++dd) s += __shfl(p, dd, 32) * ctx[dd * 32 + e];
        o[(size_t)(b * NSEQ + n) * 256 + hh * 32 + e] = (bf16_t)s;
    }
}

// ---------------- classifier head: one wave per (b, cls) ----------------
__global__ void head_kernel(const float* __restrict__ h, const float* __restrict__ Wh,
                            const float* __restrict__ bh, float* __restrict__ out) {
    int idx = blockIdx.x;                 // 0..79 = b*5 + c
    int b = idx / 5, c = idx % 5;
    int lane = threadIdx.x;
    const float* xp = h + (size_t)b * NSEQ * 256;
    float s = 0.f;
    #pragma unroll
    for (int d0 = 0; d0 < 256; d0 += 64) s += xp[d0 + lane] * Wh[(d0 + lane) * 5 + c];
    s = wave_sum(s);
    if (lane == 0) out[idx] = s + bh[c];
}

extern "C" void kernel_launch(void* const* d_in, const int* in_sizes, int n_in,
                              void* d_out, int out_size, void* d_ws, size_t ws_size,
                              hipStream_t stream) {
    const int*   x    = (const int*)d_in[0];
    const float* emb  = (const float*)d_in[1];
    const float* ch   = (const float*)d_in[2];
    const float* cls  = (const float*)d_in[3];
    const float* Wq   = (const float*)d_in[4];
    const float* Wk   = (const float*)d_in[5];
    const float* Wv   = (const float*)d_in[6];
    const float* Wo   = (const float*)d_in[7];
    const float* bo   = (const float*)d_in[8];
    const float* g1   = (const float*)d_in[9];
    const float* b1   = (const float*)d_in[10];
    const float* W1   = (const float*)d_in[11];
    const float* bf1  = (const float*)d_in[12];
    const float* W2   = (const float*)d_in[13];
    const float* bf2  = (const float*)d_in[14];
    const float* g2   = (const float*)d_in[15];
    const float* b2   = (const float*)d_in[16];
    const float* Wh   = (const float*)d_in[17];
    const float* bh   = (const float*)d_in[18];

    char* ws = (char*)d_ws;
    size_t off = 0;
    float*  h      = (float*)(ws + off);  off += (size_t)M_ * 256 * 4;            // 33,570,816
    bf16_t* yn     = (bf16_t*)(ws + off); off += (size_t)MPAD * 256 * 2;          // 16,842,752
    bf16_t* qkv    = (bf16_t*)(ws + off);
    bf16_t* f1     = (bf16_t*)(ws + off); off += (size_t)MPAD * 1024 * 2;         // 67,371,008 (f1 aliases qkv)
    float*  ctxp   = (float*)(ws + off);  off += (size_t)16 * 8 * 8 * 1024 * 4;   // 4,194,304
    float*  csump  = (float*)(ws + off);  off += (size_t)16 * 8 * 8 * 32 * 4;     // 131,072
    float*  cmax   = (float*)(ws + off);  off += (size_t)16 * 8 * 32 * 4;         // 16,384
    bf16_t* wqkv_t = (bf16_t*)(ws + off); off += (size_t)L_ * 768 * 256 * 2;      // 4,718,592
    bf16_t* wo_t   = (bf16_t*)(ws + off); off += (size_t)L_ * 256 * 256 * 2;      // 1,572,864
    bf16_t* w1_t   = (bf16_t*)(ws + off); off += (size_t)L_ * 1024 * 256 * 2;     // 6,291,456
    bf16_t* w2_t   = (bf16_t*)(ws + off); off += (size_t)L_ * 256 * 1024 * 2;     // 6,291,456
    (void)ws_size; (void)in_sizes; (void)n_in; (void)out_size;

    conv_qkv<<<9216, 256, 0, stream>>>(Wq, Wk, Wv, wqkv_t);
    conv_t<<<3072, 256, 0, stream>>>(Wo, wo_t, 256, 256);
    conv_t<<<12288, 256, 0, stream>>>(W1, w1_t, 256, 1024);
    conv_t<<<12288, 256, 0, stream>>>(W2, w2_t, 1024, 256);

    embed_kernel<<<M_ / 4, 256, 0, stream>>>(x, emb, ch, cls, h);

    for (int l = 0; l < L_; ++l) {
        // LN1 -> yn bf16
        ln_kernel<<<M_ / 4, 256, 0, stream>>>(h, g1 + l * 256, b1 + l * 256, yn);
        // QKV: yn @ wqkv^T -> qkv bf16 [M][768]
        gemm_rs<0, 4><<<dim3(6, 257), 256, 0, stream>>>(yn, wqkv_t + (size_t)l * 768 * 256,
                                                        nullptr, qkv, nullptr, 768);
        kmax_kernel<<<128, 256, 0, stream>>>(qkv, cmax);
        ctx_kernel<<<1024, 256, 0, stream>>>(qkv, cmax, ctxp, csump);
        o_kernel<<<dim3(128, 9), 256, 0, stream>>>(qkv, ctxp, csump, yn);
        // Wo: yn(attn out) @ wo^T + bo, residual += into h
        gemm_rs<1, 4><<<dim3(2, 257), 256, 0, stream>>>(yn, wo_t + (size_t)l * 256 * 256,
                                                        h, nullptr, bo + l * 256, 256);
        // LN2 -> yn bf16
        ln_kernel<<<M_ / 4, 256, 0, stream>>>(h, g2 + l * 256, b2 + l * 256, yn);
        // FF1: yn @ w1^T + bf1, gelu -> f1 bf16 [M][1024]
        gemm_rs<2, 4><<<dim3(8, 257), 256, 0, stream>>>(yn, w1_t + (size_t)l * 1024 * 256,
                                                        nullptr, f1, bf1 + l * 1024, 1024);
        // FF2: f1 @ w2^T + bf2, residual += into h
        gemm_rs<1, 16><<<dim3(2, 257), 256, 0, stream>>>(f1, w2_t + (size_t)l * 256 * 1024,
                                                         h, nullptr, bf2 + l * 256, 256);
    }

    head_kernel<<<80, 64, 0, stream>>>(h, Wh, bh, (float*)d_out);
}